// Round 10
// baseline (185.898 us; speedup 1.0000x reference)
//
#include <hip/hip_runtime.h>
#include <hip/hip_bf16.h>

namespace {

constexpr int kN = 64, kC = 128, kT = 128, kV = 25, kH = 8, kc = 16;
constexpr int kKS = 13;              // K-steps of 32 (K' = 16c * 26 = 416)
constexpr int kBCol = 448;           // output cols padded 400 -> 448
constexpr int kBRow = 36;            // B row pitch in shorts (72B: bank-spread pad)
constexpr int kBStep = kBCol * kBRow;// 16128 shorts per B k-slab (32,256 B)
constexpr int kAStep = 64 * 32;      // 2048 shorts per A k-slab (4,096 B)

typedef __attribute__((ext_vector_type(8))) short bf16x8;
typedef __attribute__((ext_vector_type(8))) unsigned short u16x8;
typedef __attribute__((ext_vector_type(4))) float f32x4;

__device__ inline unsigned short f2bf(float f) {
    unsigned int u = __builtin_bit_cast(unsigned int, f);
    u += 0x7fffu + ((u >> 16) & 1u);   // round-to-nearest-even
    return (unsigned short)(u >> 16);
}
__device__ inline float bf2f(unsigned short s) {
    return __builtin_bit_cast(float, ((unsigned int)s) << 16);
}
__device__ inline void glds16(const void* g, void* l) {
    __builtin_amdgcn_global_load_lds(
        (const __attribute__((address_space(1))) void*)g,
        (__attribute__((address_space(3))) void*)l, 16, 0, 0);
}

// ---------------- P1: w1_i[h][v][w] = fc1/||.|| + pe/||.||  (norm over v) ----
__global__ void precompute_w1(const float* __restrict__ fc1,
                              const float* __restrict__ rpe,
                              const int* __restrict__ hops,
                              float* __restrict__ W1) {
    int ih = blockIdx.x;        // i*8+h, 0..23
    int w = threadIdx.x;
    if (w >= kV) return;
    const float* f = fc1 + ih * kV * kV;
    const float* r = rpe + ih * kV;
    float s1 = 0.f, s2 = 0.f;
    for (int v = 0; v < kV; ++v) {
        float a = f[v * kV + w];
        float p = r[hops[v * kV + w]];
        s1 += a * a; s2 += p * p;
    }
    float n1 = sqrtf(s1) + 1e-4f, n2 = sqrtf(s2) + 1e-4f;
    float* o = W1 + ih * kV * kV;
    for (int v = 0; v < kV; ++v) {
        float a = f[v * kV + w];
        float p = r[hops[v * kV + w]];
        o[v * kV + w] = a / n1 + p / n2;
    }
}

// ---------------- P2: combined weight Wt4[h][k][col(448)][36] ----------------
// shorts 0..31 of a row: kappa = k*32+lo; c=kappa/26, vv=kappa%26 (25 -> 0);
// shorts 32..35: zero pad (bank spread). col<400: d=col/25, w=col%25.
__global__ void precompute_W(const float* __restrict__ W1,
                             const float* __restrict__ fc2_w,
                             unsigned short* __restrict__ Wt4) {
    int k = blockIdx.x;   // 0..12
    int h = blockIdx.y;   // 0..7
    unsigned short* outp = Wt4 + ((size_t)h * kKS + k) * kBStep;
    for (int e = threadIdx.x; e < kBStep; e += 256) {
        int col = e / kBRow, lo = e - col * kBRow;
        float val = 0.f;
        if (lo < 32 && col < 400) {
            int kap = k * 32 + lo;
            int c = kap / 26, vv = kap - c * 26;
            if (vv < 25) {
                int d = col / 25, w = col - d * 25;
                #pragma unroll
                for (int i = 0; i < 3; ++i) {
                    float wg = fc2_w[(i * kC + h * kc + d) * kc + c];
                    float w1 = W1[((i * kH + h) * kV + vv) * kV + w];
                    val += wg * w1;
                }
            }
        }
        outp[e] = f2bf(val);
    }
}

// ---------------- P0: pack x -> Xp[n][h][tb][k][t(64)][32] bf16 --------------
// dword o: p=o&15 (kappa pair 2p,2p+1), t=(o>>4)&63, rb=o>>10. Linear writes.
__global__ void pack_x(const float* __restrict__ x, unsigned int* __restrict__ Xp) {
    const int total = kN * kH * 2 * kKS * 1024;    // 13,631,488 dwords
    for (int o = blockIdx.x * blockDim.x + threadIdx.x; o < total;
         o += gridDim.x * blockDim.x) {
        int p = o & 15;
        int t = (o >> 4) & 63;
        int rb = o >> 10;                 // ((n*8+h)*2+tb)*13 + k
        int k = rb % 13; int rb2 = rb / 13;
        int tb = rb2 & 1, h = (rb2 >> 1) & 7, n = rb2 >> 4;
        int kap = k * 32 + 2 * p;         // 0..414 (k=12,p=15)
        int c0 = kap / 26, v0 = kap - c0 * 26;
        int c1 = (kap + 1) / 26, v1 = (kap + 1) - c1 * 26;
        const float* xr = x + ((size_t)(n * kC + h * kc) * kT + tb * 64 + t) * kV;
        unsigned int lo = 0, hi = 0;
        if (v0 < 25) lo = f2bf(xr[(size_t)c0 * (kT * kV) + v0]);
        if (v1 < 25) hi = f2bf(xr[(size_t)c1 * (kT * kV) + v1]);
        Xp[o] = lo | (hi << 16);
    }
}

// ---------------- MM: y = Xp * Wt4 (m97-shaped; A reg, B LDS dbuf) -----------
// block = (tb,n,h): 64 rows x 448 cols; 4 waves, each 16 rows x 448 cols
// (acc 28 x f32x4). One __syncthreads per K-step. y staged via LDS -> linear.
__global__ __launch_bounds__(256, 2) void mm(const unsigned short* __restrict__ Xp,
                                             const unsigned short* __restrict__ Wt4,
                                             float* __restrict__ y,
                                             float2* __restrict__ Pbuf) {
    __shared__ __align__(16) unsigned short Bl[2][kBStep];   // 64,512 B
    __shared__ __align__(16) float2 Bs[4 * kBCol];           // 14,336 B

    const int tb = blockIdx.x, n = blockIdx.y, h = blockIdx.z;
    const int tid = threadIdx.x, lane = tid & 63, wv = tid >> 6;
    const int ll = lane & 15, lh = lane >> 4;

    const unsigned short* abase = Xp + ((size_t)((n * kH + h) * 2 + tb) * kKS) * kAStep
                                + (size_t)(wv * 16 + ll) * 32 + lh * 8;
    const unsigned short* bbase = Wt4 + (size_t)h * kKS * kBStep;

    auto stage = [&](int k, int buf) {     // 2016 16B chunks, linear
        const unsigned short* src = bbase + (size_t)k * kBStep;
        #pragma unroll
        for (int q = 0; q < 8; ++q) {
            int e = q * 256 + tid;
            if (e < 2016) glds16(src + (size_t)e * 8, &Bl[buf][(size_t)e * 8]);
        }
    };
    auto ldA = [&](int k) -> bf16x8 {      // contiguous 1KB per wave-instr
        return *(const bf16x8*)(abase + (size_t)k * kAStep);
    };

    f32x4 acc[28];
    #pragma unroll
    for (int i = 0; i < 28; ++i) acc[i] = (f32x4)(0.f);

    stage(0, 0);
    bf16x8 aCur = ldA(0), aNxt = {};
    __syncthreads();                        // drains vmcnt: Bl[0] ready

    #pragma unroll 1
    for (int k = 0; k < kKS; ++k) {
        const int cur = k & 1;
        if (k < kKS - 1) { stage(k + 1, cur ^ 1); aNxt = ldA(k + 1); }
        #pragma unroll
        for (int ci = 0; ci < 28; ++ci) {
            bf16x8 bf = *(const bf16x8*)&Bl[cur][(size_t)(ci * 16 + ll) * kBRow + lh * 8];
            acc[ci] = __builtin_amdgcn_mfma_f32_16x16x32_bf16(aCur, bf, acc[ci], 0, 0, 0);
        }
        aCur = aNxt;
        __syncthreads();   // all reads of Bl[cur] done; stage(k+1) drained
    }

    // epilogue: acc -> Yl (bf16, reuse Bl) scatter + BN partials -> Bs
    unsigned short* Yl = &Bl[0][0];         // 16ch x 64t x 25v = 51,200 B
    #pragma unroll
    for (int ci = 0; ci < 28; ++ci) {
        int m = ci * 16 + ll;
        float s = 0.f, ss = 0.f;
        #pragma unroll
        for (int r = 0; r < 4; ++r) {
            float v = acc[ci][r];
            s += v; ss += v * v;
            if (m < 400) {
                int d = m / 25, w = m - d * 25;
                Yl[d * 1600 + (wv * 16 + lh * 4 + r) * 25 + w] = f2bf(v);
            }
        }
        s  += __shfl_xor(s, 16);  ss += __shfl_xor(ss, 16);
        s  += __shfl_xor(s, 32);  ss += __shfl_xor(ss, 32);
        if (lh == 0) Bs[wv * kBCol + m] = make_float2(s, ss);
    }
    __syncthreads();

    // copy-out: 3200 chunks of 8 bf16 -> fp32, fully linear per channel run
    const size_t ybase = ((size_t)(n * kC + h * kc) * kT + tb * 64) * kV;
    #pragma unroll
    for (int q = 0; q < 13; ++q) {
        int e = q * 256 + tid;
        if (e < 3200) {
            int d = e / 200, c = e - d * 200;
            u16x8 vv = *(const u16x8*)&Yl[(size_t)e * 8];
            f32x4 o0, o1;
            #pragma unroll
            for (int j = 0; j < 4; ++j) {
                o0[j] = bf2f((unsigned short)vv[j]);
                o1[j] = bf2f((unsigned short)vv[j + 4]);
            }
            float* yp = y + ybase + (size_t)d * (kT * kV) + c * 8;
            *(f32x4*)yp = o0;
            *(f32x4*)(yp + 4) = o1;
        }
    }

    if (tid < 16) {                         // per-channel-d partial, this block
        float s = 0.f, ss = 0.f;
        for (int w = 0; w < 25; ++w)
            #pragma unroll
            for (int u = 0; u < 4; ++u) {
                float2 p = Bs[u * kBCol + tid * 25 + w];
                s += p.x; ss += p.y;
            }
        Pbuf[(size_t)(tb + 2 * n + 128 * h) * 16 + tid] = make_float2(s, ss);
    }
}

// ---------------- B2: finalize BN stats --------------------------------------
__global__ void bn_finalize(const float2* __restrict__ Pbuf,
                            const float* __restrict__ gamma,
                            const float* __restrict__ beta,
                            float2* __restrict__ scsh) {
    int ch = threadIdx.x;
    if (ch >= kC) return;
    int h = ch >> 4, d = ch & 15;
    float s = 0.f, ss = 0.f;
    for (int j = 0; j < 128; ++j) {          // j = tb + 2n
        float2 p = Pbuf[(size_t)(j + 128 * h) * 16 + d];
        s += p.x; ss += p.y;
    }
    const float inv = 1.f / (float)(kN * kT * kV);
    float mean = s * inv;
    float var  = ss * inv - mean * mean;
    float sc = gamma[ch] * rsqrtf(var + 1e-5f);
    scsh[ch] = make_float2(sc, beta[ch] - mean * sc);
}

// ---------------- C: out = relu(y*scale + shift + x), in place on d_out ------
__global__ void bn_apply(float* __restrict__ y, const float* __restrict__ x,
                         const float2* __restrict__ scsh) {
    const size_t total4 = (size_t)kN * kC * kT * kV / 4;   // 6,553,600
    for (size_t i = (size_t)blockIdx.x * blockDim.x + threadIdx.x; i < total4;
         i += (size_t)gridDim.x * blockDim.x) {
        int ch = (int)((i / 800) % kC);          // T*V/4 = 800 f32x4 per (n,ch)
        float2 sc = scsh[ch];
        f32x4 yv = ((const f32x4*)y)[i];
        f32x4 xv = ((const f32x4*)x)[i];
        f32x4 o;
        #pragma unroll
        for (int q = 0; q < 4; ++q)
            o[q] = fmaxf(yv[q] * sc.x + sc.y + xv[q], 0.f);
        ((f32x4*)y)[i] = o;
    }
}

} // namespace

extern "C" void kernel_launch(void* const* d_in, const int* in_sizes, int n_in,
                              void* d_out, int out_size, void* d_ws, size_t ws_size,
                              hipStream_t stream) {
    const float* x     = (const float*)d_in[0];
    const float* fc1   = (const float*)d_in[1];
    const float* rpe   = (const float*)d_in[2];
    const int*   hops  = (const int*)d_in[3];
    const float* fc2w  = (const float*)d_in[4];
    // d_in[5] = fc2_b: constant over BN reduction axes -> cancelled by BN.
    const float* gamma = (const float*)d_in[6];
    const float* beta  = (const float*)d_in[7];
    float* out = (float*)d_out;

    char* ws = (char*)d_ws;
    float*          W1   = (float*)ws;                       // 60,000 B (pad 64K)
    unsigned short* Wt4  = (unsigned short*)(ws + 65536);    // 3,354,624 B
    unsigned int*   Xp   = (unsigned int*)(ws + 3420160);    // 54,525,952 B
    float2*         Pbuf = (float2*)(ws + 57946112);         // 131,072 B
    float2*         scsh = (float2*)(ws + 58077184);         // 1,024 B

    precompute_w1<<<24, 32, 0, stream>>>(fc1, rpe, hops, W1);
    precompute_W<<<dim3(13, 8), 256, 0, stream>>>(W1, fc2w, Wt4);
    pack_x<<<2048, 256, 0, stream>>>(x, Xp);
    mm<<<dim3(2, 64, 8), 256, 0, stream>>>((const unsigned short*)Xp, Wt4, out, Pbuf);
    bn_finalize<<<1, 128, 0, stream>>>(Pbuf, gamma, beta, scsh);
    bn_apply<<<2048, 256, 0, stream>>>(out, x, scsh);
}